// Round 3
// baseline (29.160 us; speedup 1.0000x reference)
//
#include <hip/hip_runtime.h>
#include <hip/hip_bf16.h>

// x: (b=16, c=2, d=64, w=128, h=128) f32.
// out[b] = 0                         if x_flag[b] <= 0.5
//        = flip_h(x[b])              if x_flag[b] > 0.5 && y_flag[b] <= 0.5
//        = flip_w(flip_h(x[b]))      if both > 0.5
// Reference casts to float16; harness stores non-bf16 outputs as FLOAT32
// (header: "bfloat16 -> __hip_bfloat16*, else float*"). So write f32 values
// passed through an f16 round-trip to match the reference cast bit-exactly.

typedef __attribute__((ext_vector_type(4))) float float4v;

__global__ __launch_bounds__(256) void Mirror_kernel(
    const float* __restrict__ x,
    const float* __restrict__ x_flag,
    const float* __restrict__ y_flag,
    float* __restrict__ out,
    int total4)
{
    const int stride = gridDim.x * blockDim.x;
    for (int i = blockIdx.x * blockDim.x + threadIdx.x; i < total4; i += stride) {
        // i indexes 4-element chunks along h (32 chunks per 128-wide h row).
        const int h4  = i & 31;          // which 4-chunk along h
        const int w   = (i >> 5) & 127;  // w index
        const int bcd = i >> 12;         // b*128 + c*64 + d
        const int b   = bcd >> 7;

        float4v o;
        const float fx = x_flag[b];
        if (!(fx > 0.5f)) {
            o = (float4v)0.0f;
        } else {
            const int w_src = (y_flag[b] > 0.5f) ? (127 - w) : w;
            // out h positions [4*h4 .. 4*h4+3] <- x h positions [127-4*h4 .. 124-4*h4]
            const size_t base = (((size_t)bcd * 128 + (size_t)w_src) * 128)
                              + (size_t)(124 - 4 * h4);
            const float4v s = *reinterpret_cast<const float4v*>(x + base);
            o[0] = s[3]; o[1] = s[2]; o[2] = s[1]; o[3] = s[0];
            #pragma unroll
            for (int j = 0; j < 4; ++j)
                o[j] = (float)(_Float16)o[j];   // emulate .astype(float16)
        }
        *reinterpret_cast<float4v*>(out + (size_t)i * 4) = o;
    }
}

extern "C" void kernel_launch(void* const* d_in, const int* in_sizes, int n_in,
                              void* d_out, int out_size, void* d_ws, size_t ws_size,
                              hipStream_t stream) {
    const float* x      = (const float*)d_in[0];
    const float* x_flag = (const float*)d_in[1];
    const float* y_flag = (const float*)d_in[2];
    float* out          = (float*)d_out;

    const int total4 = in_sizes[0] / 4;  // 8,388,608 chunks of 4 h-elements
    const int block = 256;
    const int grid = 4096;               // grid-stride, 8 iters/thread
    Mirror_kernel<<<grid, block, 0, stream>>>(x, x_flag, y_flag, out, total4);
}